// Round 1
// baseline (152.456 us; speedup 1.0000x reference)
//
#include <hip/hip_runtime.h>
#include <hip/hip_bf16.h>

#define HALF 4096
#define NTOT 8192
#define D 128
#define LSTR 136                     // 128 + 8 pad (keeps 16B alignment: 272B rows)
#define KSCALE 14.426950408889634f   // log2(e)/T, T=0.1

typedef __attribute__((ext_vector_type(8))) short bf16x8;
typedef __attribute__((ext_vector_type(4))) float f32x4;

__device__ __forceinline__ float wave_sum64(float v) {
#pragma unroll
    for (int m = 32; m >= 1; m >>= 1) v += __shfl_xor(v, m);
    return v;
}

__global__ void cast_kernel(const float* __restrict__ f1, const float* __restrict__ f2,
                            __hip_bfloat16* __restrict__ xb) {
    int i = blockIdx.x * blockDim.x + threadIdx.x;   // grid covers exactly NTOT*D
    float v = (i < HALF * D) ? f1[i] : f2[i - HALF * D];
    xb[i] = __float2bfloat16(v);
}

// exact fp32 positive-pair scaled dot: spos[i] = <x_i, x_{(i+HALF)%N}> / T
__global__ void pos_kernel(const float* __restrict__ f1, const float* __restrict__ f2,
                           float* __restrict__ spos) {
    int i = blockIdx.x;
    int l = threadIdx.x;              // 64 threads
    int p = (i < HALF) ? i + HALF : i - HALF;
    const float* xi = (i < HALF) ? (f1 + (size_t)i * D) : (f2 + (size_t)(i - HALF) * D);
    const float* xp = (p < HALF) ? (f1 + (size_t)p * D) : (f2 + (size_t)(p - HALF) * D);
    float d = xi[l] * xp[l] + xi[l + 64] * xp[l + 64];
    d = wave_sum64(d);
    if (l == 0) spos[i] = d * 10.0f;
}

// One Gram pass over lower-triangular 128x128 tiles; accumulates
// E1[i] = sum_{j!=i} exp(s_ij), E2[i] = sum_{j!=i} exp(s_ij)^2 via atomics.
__global__ __launch_bounds__(256, 2) void gram_kernel(const __hip_bfloat16* __restrict__ xb,
                                                      float* __restrict__ E1,
                                                      float* __restrict__ E2) {
    __shared__ __align__(16) __hip_bfloat16 As[128][LSTR];
    __shared__ __align__(16) __hip_bfloat16 Bs[128][LSTR];

    // decode lower-triangular pair (a >= b), 64*65/2 = 2080 blocks
    int L = blockIdx.x;
    int a = (int)((sqrtf(8.0f * (float)L + 1.0f) - 1.0f) * 0.5f);
    while ((a + 1) * (a + 2) / 2 <= L) ++a;
    while (a * (a + 1) / 2 > L) --a;
    int b = L - a * (a + 1) / 2;
    const int rowBase = a * 128;
    const int colBase = b * 128;
    const bool offdiag = (a != b);

    const int t = threadIdx.x;
    {   // stage A,B panels: thread t loads row t>>1, 8 chunks of 16B each
        int r  = t >> 1;
        int c0 = (t & 1) * 8;
        const int4* gA = (const int4*)(xb + (size_t)(rowBase + r) * D);
        const int4* gB = (const int4*)(xb + (size_t)(colBase + r) * D);
        int4* lA = (int4*)(&As[r][0]);
        int4* lB = (int4*)(&Bs[r][0]);
#pragma unroll
        for (int c = 0; c < 8; ++c) {
            lA[c0 + c] = gA[c0 + c];
            lB[c0 + c] = gB[c0 + c];
        }
    }
    __syncthreads();

    const int wave = t >> 6, lane = t & 63;
    const int wr = (wave & 1) * 64, wc = (wave >> 1) * 64;
    const int lrow = lane & 15, quad = lane >> 4;

    f32x4 acc[4][4];
#pragma unroll
    for (int r = 0; r < 4; ++r)
#pragma unroll
        for (int c = 0; c < 4; ++c)
            acc[r][c] = (f32x4){0.f, 0.f, 0.f, 0.f};

#pragma unroll
    for (int k0 = 0; k0 < 128; k0 += 32) {
        bf16x8 af[4], bfr[4];
#pragma unroll
        for (int r = 0; r < 4; ++r)
            af[r] = *(const bf16x8*)(&As[wr + r * 16 + lrow][k0 + quad * 8]);
#pragma unroll
        for (int c = 0; c < 4; ++c)
            bfr[c] = *(const bf16x8*)(&Bs[wc + c * 16 + lrow][k0 + quad * 8]);
#pragma unroll
        for (int r = 0; r < 4; ++r)
#pragma unroll
            for (int c = 0; c < 4; ++c)
                acc[r][c] = __builtin_amdgcn_mfma_f32_16x16x32_bf16(af[r], bfr[c], acc[r][c], 0, 0, 0);
    }

    // epilogue: e = exp2(s*KSCALE); row partials (r,reg) and col partials (c)
    float rs1[4][4], rs2[4][4], cs1[4], cs2[4];
#pragma unroll
    for (int r = 0; r < 4; ++r)
#pragma unroll
        for (int g = 0; g < 4; ++g) { rs1[r][g] = 0.f; rs2[r][g] = 0.f; }
#pragma unroll
    for (int c = 0; c < 4; ++c) { cs1[c] = 0.f; cs2[c] = 0.f; }

#pragma unroll
    for (int r = 0; r < 4; ++r) {
#pragma unroll
        for (int c = 0; c < 4; ++c) {
            int gcol = colBase + wc + c * 16 + lrow;
#pragma unroll
            for (int g = 0; g < 4; ++g) {
                int grow = rowBase + wr + r * 16 + quad * 4 + g;
                float e = exp2f(acc[r][c][g] * KSCALE);
                e = (grow == gcol) ? 0.0f : e;   // mask diagonal before squaring
                float e2 = e * e;
                rs1[r][g] += e;  rs2[r][g] += e2;
                cs1[c]    += e;  cs2[c]    += e2;
            }
        }
    }

    // row sums: reduce across the 16 lanes sharing a quad (low-4 xor)
#pragma unroll
    for (int r = 0; r < 4; ++r) {
#pragma unroll
        for (int g = 0; g < 4; ++g) {
            float v1 = rs1[r][g], v2 = rs2[r][g];
#pragma unroll
            for (int m = 1; m <= 8; m <<= 1) { v1 += __shfl_xor(v1, m); v2 += __shfl_xor(v2, m); }
            if (lrow == 0) {
                int grow = rowBase + wr + r * 16 + quad * 4 + g;
                atomicAdd(&E1[grow], v1);
                atomicAdd(&E2[grow], v2);
            }
        }
    }
    // col sums (transpose contribution, off-diagonal tiles only):
    // reduce across quads (xor 16, 32); lanes 0..15 hold per-column sums
    if (offdiag) {
#pragma unroll
        for (int c = 0; c < 4; ++c) {
            float v1 = cs1[c], v2 = cs2[c];
            v1 += __shfl_xor(v1, 16); v2 += __shfl_xor(v2, 16);
            v1 += __shfl_xor(v1, 32); v2 += __shfl_xor(v2, 32);
            if (quad == 0) {
                int gcol = colBase + wc + c * 16 + lrow;
                atomicAdd(&E1[gcol], v1);
                atomicAdd(&E2[gcol], v2);
            }
        }
    }
}

// per-row closed-form terms; series for sum_j log1p(-P_ij) = -(1 + S2/2 + O(S3))
__global__ void rowterm_kernel(const float* __restrict__ E1, const float* __restrict__ E2,
                               const float* __restrict__ spos, float* __restrict__ acc) {
    int i = blockIdx.x * blockDim.x + threadIdx.x;   // 32 blocks x 256
    float div = E1[i];
    float S2 = E2[i] / (div * div);
    float sp = spos[i];
    float lnPmt = __expf(sp) / div;
    float term = sp - __logf(div)          // log(lnPmt_i)
               - 1.0f - 0.5f * S2          // sum_j log1p(-Pon_ij)
               - __logf(1.0f - lnPmt);     // minus log1p(-lnPmt_i)
    term = wave_sum64(term);
    if ((threadIdx.x & 63) == 0) atomicAdd(acc, term);
}

__global__ void fin_kernel(const float* __restrict__ acc, float* __restrict__ out) {
    out[0] = -acc[0] * (1.0f / (float)NTOT);
}

extern "C" void kernel_launch(void* const* d_in, const int* in_sizes, int n_in,
                              void* d_out, int out_size, void* d_ws, size_t ws_size,
                              hipStream_t stream) {
    const float* f1 = (const float*)d_in[0];
    const float* f2 = (const float*)d_in[1];
    float* out = (float*)d_out;

    char* ws = (char*)d_ws;
    __hip_bfloat16* xb = (__hip_bfloat16*)ws;                 // 8192*128*2 = 2 MB
    float* E1   = (float*)(ws + (size_t)NTOT * D * 2);        // 8192 f32
    float* E2   = E1 + NTOT;                                  // 8192 f32
    float* spos = E2 + NTOT;                                  // 8192 f32
    float* acc  = spos + NTOT;                                // 1 f32

    // zero E1, E2, (spos — overwritten anyway), acc in one shot
    hipMemsetAsync(E1, 0, (size_t)(3 * NTOT + 1) * sizeof(float), stream);

    cast_kernel<<<(NTOT * D) / 256, 256, 0, stream>>>(f1, f2, xb);
    pos_kernel<<<NTOT, 64, 0, stream>>>(f1, f2, spos);
    gram_kernel<<<(64 * 65) / 2, 256, 0, stream>>>(xb, E1, E2);
    rowterm_kernel<<<NTOT / 256, 256, 0, stream>>>(E1, E2, spos, acc);
    fin_kernel<<<1, 1, 0, stream>>>(acc, out);
}

// Round 2
// 120.222 us; speedup vs baseline: 1.2681x; 1.2681x over previous
//
#include <hip/hip_runtime.h>
#include <hip/hip_bf16.h>

#define HALF 4096
#define NTOT 8192
#define D 128
#define LSTR 136                    // 128 + 8 pad; 272B rows keep 16B alignment
#define KSQ 3.16227766016838f       // sqrt(10): <KSQ*x, KSQ*x> = <x,x>/T, T=0.1

typedef __attribute__((ext_vector_type(8))) short bf16x8;
typedef __attribute__((ext_vector_type(4))) float f32x4;

__device__ __forceinline__ float wave_sum64(float v) {
#pragma unroll
    for (int m = 32; m >= 1; m >>= 1) v += __shfl_xor(v, m);
    return v;
}

__device__ __forceinline__ ushort2 tobf2(float2 v) {
    __hip_bfloat16 lo = __float2bfloat16(v.x);
    __hip_bfloat16 hi = __float2bfloat16(v.y);
    ushort2 r;
    r.x = *(unsigned short*)&lo;
    r.y = *(unsigned short*)&hi;
    return r;
}

// One wave per pair b: cast rows b (f1) and b+HALF (f2) to bf16*sqrt(10),
// and compute the shared positive dot spos[b] = spos[b+HALF] = <f1_b,f2_b>/T.
__global__ void cast_pos_kernel(const float* __restrict__ f1, const float* __restrict__ f2,
                                unsigned short* __restrict__ xs, float* __restrict__ spos) {
    int w = (blockIdx.x * blockDim.x + threadIdx.x) >> 6;   // pair index b, 0..4095
    int l = threadIdx.x & 63;
    float2 a1 = ((const float2*)(f1 + (size_t)w * D))[l];
    float2 a2 = ((const float2*)(f2 + (size_t)w * D))[l];
    ((ushort2*)(xs + (size_t)w * D))[l]          = tobf2(make_float2(a1.x * KSQ, a1.y * KSQ));
    ((ushort2*)(xs + (size_t)(w + HALF) * D))[l] = tobf2(make_float2(a2.x * KSQ, a2.y * KSQ));
    float d = a1.x * a2.x + a1.y * a2.y;
    d = wave_sum64(d);
    if (l == 0) { spos[w] = d * 10.0f; spos[w + HALF] = d * 10.0f; }
}

// Row-panel Gram sweep. Block (slab, panel): rows panel*128..+127, col tiles
// slab*8..slab*8+7. Accumulates E1 partial row sums in registers across the
// sweep; writes disjoint slot (slab*2 + wavepair) of E1p — no atomics.
__global__ __launch_bounds__(256, 2) void gram_kernel(const unsigned short* __restrict__ xs,
                                                      float* __restrict__ E1p) {
    __shared__ __align__(16) __hip_bfloat16 As[128][LSTR];
    __shared__ __align__(16) __hip_bfloat16 Bs[128][LSTR];

    const int slab = blockIdx.x;    // 0..7
    const int panel = blockIdx.y;   // 0..63
    const int t = threadIdx.x;
    const int sr = t >> 1, sc0 = (t & 1) * 8;   // staging: row, 8x16B chunk base

    {   // stage A panel and first B tile
        const int4* gA = (const int4*)(xs + ((size_t)panel * 128 + sr) * D);
        const int4* gB = (const int4*)(xs + ((size_t)slab * 8 * 128 + sr) * D);
        int4* lA = (int4*)(&As[sr][0]);
        int4* lB = (int4*)(&Bs[sr][0]);
#pragma unroll
        for (int c = 0; c < 8; ++c) { lA[sc0 + c] = gA[sc0 + c]; lB[sc0 + c] = gB[sc0 + c]; }
    }
    __syncthreads();

    const int wave = t >> 6, lane = t & 63;
    const int wr = (wave & 1) * 64, wc = (wave >> 1) * 64;
    const int lrow = lane & 15, quad = lane >> 4;

    // hoist A fragments for all 4 k-steps (LDS -> 64 VGPRs, read once)
    bf16x8 af[4][4];
#pragma unroll
    for (int k = 0; k < 4; ++k)
#pragma unroll
        for (int r = 0; r < 4; ++r)
            af[k][r] = *(const bf16x8*)(&As[wr + r * 16 + lrow][k * 32 + quad * 8]);

    float rs[4][4];
#pragma unroll
    for (int r = 0; r < 4; ++r)
#pragma unroll
        for (int g = 0; g < 4; ++g) rs[r][g] = 0.f;

    int4 pf[8];
    for (int tt = 0; tt < 8; ++tt) {
        if (tt < 7) {   // prefetch next B tile into registers (overlaps compute)
            const int4* gB = (const int4*)(xs + ((size_t)(slab * 8 + tt + 1) * 128 + sr) * D);
#pragma unroll
            for (int c = 0; c < 8; ++c) pf[c] = gB[sc0 + c];
        }

        f32x4 acc[4][4];
#pragma unroll
        for (int r = 0; r < 4; ++r)
#pragma unroll
            for (int c = 0; c < 4; ++c) acc[r][c] = (f32x4){0.f, 0.f, 0.f, 0.f};

#pragma unroll
        for (int k = 0; k < 4; ++k) {
            bf16x8 bfr[4];
#pragma unroll
            for (int c = 0; c < 4; ++c)
                bfr[c] = *(const bf16x8*)(&Bs[wc + c * 16 + lrow][k * 32 + quad * 8]);
#pragma unroll
            for (int r = 0; r < 4; ++r)
#pragma unroll
                for (int c = 0; c < 4; ++c)
                    acc[r][c] = __builtin_amdgcn_mfma_f32_16x16x32_bf16(af[k][r], bfr[c], acc[r][c], 0, 0, 0);
        }

        const bool diag = (slab * 8 + tt == panel);   // wave-uniform
#pragma unroll
        for (int r = 0; r < 4; ++r) {
#pragma unroll
            for (int c = 0; c < 4; ++c) {
#pragma unroll
                for (int g = 0; g < 4; ++g) {
                    float e = __expf(acc[r][c][g]);   // acc is already s_ij
                    if (diag) {
                        int ri = wr + r * 16 + quad * 4 + g;
                        int ci = wc + c * 16 + lrow;
                        e = (ri == ci) ? 0.0f : e;
                    }
                    rs[r][g] += e;
                }
            }
        }

        if (tt < 7) {
            __syncthreads();            // everyone done reading Bs
            int4* lB = (int4*)(&Bs[sr][0]);
#pragma unroll
            for (int c = 0; c < 8; ++c) lB[sc0 + c] = pf[c];
            __syncthreads();
        }
    }

    // one reduction over the 16 lanes sharing a quad, one plain store
    const int slot = slab * 2 + (wave >> 1);
#pragma unroll
    for (int r = 0; r < 4; ++r) {
#pragma unroll
        for (int g = 0; g < 4; ++g) {
            float v = rs[r][g];
#pragma unroll
            for (int m = 1; m <= 8; m <<= 1) v += __shfl_xor(v, m);
            if (lrow == 0)
                E1p[(size_t)slot * NTOT + panel * 128 + wr + r * 16 + quad * 4 + g] = v;
        }
    }
}

// Single block: sum 16 partials per row, per-row closed form, block reduce.
// sum_j log1p(-P_ij) ~= -1 (sum_j P_ij == 1 exactly; S2/2 ~ 1.3e-4 dropped)
__global__ void fin_kernel(const float* __restrict__ E1p, const float* __restrict__ spos,
                           float* __restrict__ out) {
    int t = threadIdx.x;   // 1024
    float local = 0.f;
#pragma unroll
    for (int ch = 0; ch < 8; ++ch) {
        int i = ch * 1024 + t;
        float div = 0.f;
#pragma unroll
        for (int s = 0; s < 16; ++s) div += E1p[(size_t)s * NTOT + i];
        float sp = spos[i];
        float pmt = __expf(sp) / div;
        local += sp - __logf(div) - 1.0f - __logf(1.0f - pmt);
    }
    local = wave_sum64(local);
    __shared__ float red[16];
    if ((t & 63) == 0) red[t >> 6] = local;
    __syncthreads();
    if (t < 64) {
        float v = (t < 16) ? red[t] : 0.f;
        v = wave_sum64(v);
        if (t == 0) out[0] = -v * (1.0f / (float)NTOT);
    }
}

extern "C" void kernel_launch(void* const* d_in, const int* in_sizes, int n_in,
                              void* d_out, int out_size, void* d_ws, size_t ws_size,
                              hipStream_t stream) {
    const float* f1 = (const float*)d_in[0];
    const float* f2 = (const float*)d_in[1];
    float* out = (float*)d_out;

    char* ws = (char*)d_ws;
    unsigned short* xs = (unsigned short*)ws;                 // 8192*128*2B = 2 MB
    float* E1p  = (float*)(ws + (size_t)NTOT * D * 2);        // 16*8192 f32 = 512 KB
    float* spos = E1p + 16 * NTOT;                            // 8192 f32

    cast_pos_kernel<<<1024, 256, 0, stream>>>(f1, f2, xs, spos);
    gram_kernel<<<dim3(8, 64), 256, 0, stream>>>(xs, E1p);
    fin_kernel<<<1, 1024, 0, stream>>>(E1p, spos, out);
}

// Round 3
// 106.649 us; speedup vs baseline: 1.4295x; 1.1273x over previous
//
#include <hip/hip_runtime.h>
#include <hip/hip_bf16.h>

#define HALF 4096
#define NTOT 8192
#define D 128
#define KSQ 3.16227766016838f       // sqrt(10): <KSQ*x, KSQ*x> = <x,x>/T, T=0.1

typedef __attribute__((ext_vector_type(8))) short bf16x8;
typedef __attribute__((ext_vector_type(4))) float f32x4;

__device__ __forceinline__ float wave_sum64(float v) {
#pragma unroll
    for (int m = 32; m >= 1; m >>= 1) v += __shfl_xor(v, m);
    return v;
}

__device__ __forceinline__ ushort2 tobf2(float2 v) {
    __hip_bfloat16 lo = __float2bfloat16(v.x);
    __hip_bfloat16 hi = __float2bfloat16(v.y);
    ushort2 r;
    r.x = *(unsigned short*)&lo;
    r.y = *(unsigned short*)&hi;
    return r;
}

// One wave per pair b: cast rows b (f1) and b+HALF (f2) to bf16*sqrt(10),
// and compute the shared positive dot spos[b] = spos[b+HALF] = <f1_b,f2_b>/T.
__global__ void cast_pos_kernel(const float* __restrict__ f1, const float* __restrict__ f2,
                                unsigned short* __restrict__ xs, float* __restrict__ spos) {
    int w = (blockIdx.x * blockDim.x + threadIdx.x) >> 6;   // pair index b, 0..4095
    int l = threadIdx.x & 63;
    float2 a1 = ((const float2*)(f1 + (size_t)w * D))[l];
    float2 a2 = ((const float2*)(f2 + (size_t)w * D))[l];
    ((ushort2*)(xs + (size_t)w * D))[l]          = tobf2(make_float2(a1.x * KSQ, a1.y * KSQ));
    ((ushort2*)(xs + (size_t)(w + HALF) * D))[l] = tobf2(make_float2(a2.x * KSQ, a2.y * KSQ));
    float d = a1.x * a2.x + a1.y * a2.y;
    d = wave_sum64(d);
    if (l == 0) { spos[w] = d * 10.0f; spos[w + HALF] = d * 10.0f; }
}

// LDS-free, barrier-free Gram row-sum sweep. Input is 2 MB -> L2-resident.
// Block (slab, panel): rows panel*128..+127, col tiles slab*8..slab*8+7.
// Wave w: rows wr=(w&1)*64, cols wc=(w>>1)*64 of each 128x128 tile.
// A fragments hoisted to 64 VGPRs once; B fragments loaded straight from
// global (L2) each k-step. exp row-sums accumulate in registers across the
// whole sweep; one shuffle-reduce + disjoint-slot store at the end.
__global__ __launch_bounds__(256, 2) void gram_kernel(const unsigned short* __restrict__ xs,
                                                      float* __restrict__ E1p) {
    const int slab = blockIdx.x;    // 0..7
    const int panel = blockIdx.y;   // 0..63
    const int t = threadIdx.x;
    const int wave = t >> 6, lane = t & 63;
    const int wr = (wave & 1) * 64, wc = (wave >> 1) * 64;
    const int lrow = lane & 15, quad = lane >> 4;

    // hoist A fragments: A[row = panel*128+wr+r*16+lrow][k = k*32+quad*8 ..+8]
    const unsigned short* abase = xs + ((size_t)panel * 128 + wr + lrow) * D + quad * 8;
    bf16x8 af[4][4];
#pragma unroll
    for (int k = 0; k < 4; ++k)
#pragma unroll
        for (int r = 0; r < 4; ++r)
            af[k][r] = *(const bf16x8*)(abase + (size_t)r * 16 * D + k * 32);

    float rs[4][4];
#pragma unroll
    for (int r = 0; r < 4; ++r)
#pragma unroll
        for (int g = 0; g < 4; ++g) rs[r][g] = 0.f;

    for (int tt = 0; tt < 8; ++tt) {
        const unsigned short* bbase =
            xs + ((size_t)(slab * 8 + tt) * 128 + wc + lrow) * D + quad * 8;

        f32x4 acc[4][4];
#pragma unroll
        for (int r = 0; r < 4; ++r)
#pragma unroll
            for (int c = 0; c < 4; ++c) acc[r][c] = (f32x4){0.f, 0.f, 0.f, 0.f};

#pragma unroll
        for (int k = 0; k < 4; ++k) {
            bf16x8 bfr[4];
#pragma unroll
            for (int c = 0; c < 4; ++c)
                bfr[c] = *(const bf16x8*)(bbase + (size_t)c * 16 * D + k * 32);
#pragma unroll
            for (int r = 0; r < 4; ++r)
#pragma unroll
                for (int c = 0; c < 4; ++c)
                    acc[r][c] = __builtin_amdgcn_mfma_f32_16x16x32_bf16(af[k][r], bfr[c], acc[r][c], 0, 0, 0);
        }

        const bool diag = (slab * 8 + tt == panel);   // wave-uniform
#pragma unroll
        for (int r = 0; r < 4; ++r) {
#pragma unroll
            for (int c = 0; c < 4; ++c) {
#pragma unroll
                for (int g = 0; g < 4; ++g) {
                    float e = __expf(acc[r][c][g]);   // acc is already s_ij
                    if (diag) {
                        int ri = wr + r * 16 + quad * 4 + g;
                        int ci = wc + c * 16 + lrow;
                        e = (ri == ci) ? 0.0f : e;
                    }
                    rs[r][g] += e;
                }
            }
        }
    }

    // reduce over the 16 lanes sharing a quad; store disjoint partial slot
    const int slot = slab * 2 + (wave >> 1);
#pragma unroll
    for (int r = 0; r < 4; ++r) {
#pragma unroll
        for (int g = 0; g < 4; ++g) {
            float v = rs[r][g];
#pragma unroll
            for (int m = 1; m <= 8; m <<= 1) v += __shfl_xor(v, m);
            if (lrow == 0)
                E1p[(size_t)slot * NTOT + panel * 128 + wr + r * 16 + quad * 4 + g] = v;
        }
    }
}

// Single block: sum 16 partials per row, per-row closed form, block reduce.
// sum_j log1p(-P_ij) ~= -1 (sum_j P_ij == 1 exactly; S2/2 ~ 1.3e-4 dropped)
__global__ void fin_kernel(const float* __restrict__ E1p, const float* __restrict__ spos,
                           float* __restrict__ out) {
    int t = threadIdx.x;   // 1024
    float local = 0.f;
#pragma unroll
    for (int ch = 0; ch < 8; ++ch) {
        int i = ch * 1024 + t;
        float div = 0.f;
#pragma unroll
        for (int s = 0; s < 16; ++s) div += E1p[(size_t)s * NTOT + i];
        float sp = spos[i];
        float pmt = __expf(sp) / div;
        local += sp - __logf(div) - 1.0f - __logf(1.0f - pmt);
    }
    local = wave_sum64(local);
    __shared__ float red[16];
    if ((t & 63) == 0) red[t >> 6] = local;
    __syncthreads();
    if (t < 64) {
        float v = (t < 16) ? red[t] : 0.f;
        v = wave_sum64(v);
        if (t == 0) out[0] = -v * (1.0f / (float)NTOT);
    }
}

extern "C" void kernel_launch(void* const* d_in, const int* in_sizes, int n_in,
                              void* d_out, int out_size, void* d_ws, size_t ws_size,
                              hipStream_t stream) {
    const float* f1 = (const float*)d_in[0];
    const float* f2 = (const float*)d_in[1];
    float* out = (float*)d_out;

    char* ws = (char*)d_ws;
    unsigned short* xs = (unsigned short*)ws;                 // 8192*128*2B = 2 MB
    float* E1p  = (float*)(ws + (size_t)NTOT * D * 2);        // 16*8192 f32 = 512 KB
    float* spos = E1p + 16 * NTOT;                            // 8192 f32

    cast_pos_kernel<<<1024, 256, 0, stream>>>(f1, f2, xs, spos);
    gram_kernel<<<dim3(8, 64), 256, 0, stream>>>(xs, E1p);
    fin_kernel<<<1, 1024, 0, stream>>>(E1p, spos, out);
}